// Round 12
// baseline (245.001 us; speedup 1.0000x reference)
//
#include <hip/hip_runtime.h>

#define NN 128
#define CCH 16
#define BB 4
#define HID 128
#define DOUT 128

// ---------------------------------------------------------------------------
// Shared body. Block = (b, row p), 1024 threads = 16 waves, 2 blocks/CU.
// Phase 1: wave = channel c (wave-uniform); lane owns q-pair {2*lane, 2*lane+1}.
//   Pure-scalar k-loop: 13 VALU/k/thread (6.5 per cell), weights are s_load
//   SGPRs embedded directly as VOP3 operands (1 SGPR per fma — legal), the
//   a = w.x*xpp + b1k term shared across the q-pair. No v2f splats.
// Diag: mask q==p, 64-lane shuffle reduce per wave.
// Phase 2: wave wv -> d = wv*8..+7 (scalar Wc/bc loads), lane = m-pair. Scalar.
// REP>1 (shadow only): repeat k-loop with eps perturbation; results kept live
//   via empty asm (DCE guard, rule #17).
// ---------------------------------------------------------------------------
template<int REP>
__device__ __forceinline__ void rey_body(
    const float* __restrict__ x,
    const float* __restrict__ W1, const float* __restrict__ b1,
    const float* __restrict__ W2, const float* __restrict__ b2,
    const float* __restrict__ Wc, const float* __restrict__ bc,
    float* __restrict__ y)
{
    __shared__ float s_out[CCH][NN];   // 8 KB
    __shared__ float s_diag[CCH];

    const int t    = threadIdx.x;
    const int bid  = blockIdx.x;
    const int p    = bid & 127;
    const int b    = bid >> 7;
    const int c    = t >> 6;           // 0..15, wave-uniform
    const int lane = t & 63;
    const int q0   = lane * 2;

    const float* xm = x + ((size_t)(b * CCH + c) << 14);

    // per-thread x loads
    const float2 vpq = *reinterpret_cast<const float2*>(&xm[p * NN + q0]); // coalesced
    float xpq0 = vpq.x, xpq1 = vpq.y;
    const float xqp0 = xm[q0 * NN + p];        // strided (column)
    const float xqp1 = xm[(q0 + 1) * NN + p];
    const float xqq0 = xm[q0 * (NN + 1)];      // strided (diagonal)
    const float xqq1 = xm[(q0 + 1) * (NN + 1)];
    const float xpp  = xm[p * (NN + 1)];       // wave-uniform -> scalar load

    const float bb0 = b2[0], bb1 = b2[1];
    float h0a = 0.f, h0b = 0.f, h1a = 0.f, h1b = 0.f;

    #pragma unroll 1
    for (int r = 0; r < REP; ++r) {
        if (REP > 1) { xpq0 += 1e-7f; xpq1 += 1e-7f; }   // defeat cross-rep CSE
        h0a = 0.f; h0b = 0.f; h1a = 0.f; h1b = 0.f;
        #pragma unroll 4
        for (int k = 0; k < HID; ++k) {
            const float4 w  = reinterpret_cast<const float4*>(W1)[k];  // s_load x4
            const float b1k = b1[k];
            const float w20 = W2[k];
            const float w21 = W2[HID + k];
            const float a = fmaf(w.x, xpp, b1k);   // shared across the q-pair
            float u = fmaf(w.y, xpq0, a);
            u = fmaf(w.z, xqp0, u);
            u = fmaf(w.w, xqq0, u);
            u = fmaxf(u, 0.f);
            h0a = fmaf(w20, u, h0a);
            h1a = fmaf(w21, u, h1a);
            float v = fmaf(w.y, xpq1, a);
            v = fmaf(w.z, xqp1, v);
            v = fmaf(w.w, xqq1, v);
            v = fmaxf(v, 0.f);
            h0b = fmaf(w20, v, h0b);
            h1b = fmaf(w21, v, h1b);
        }
        if (REP > 1)   // keep each rep's results live without memory traffic
            asm volatile("" :: "v"(h0a), "v"(h0b), "v"(h1a), "v"(h1b));
    }

    // off-diagonal h1 (+b2[1]) -> LDS row c; (c,p) slot fixed after barrier
    s_out[c][q0]     = h1a + bb1;
    s_out[c][q0 + 1] = h1b + bb1;

    // diag partial: mask q==p, 64-lane wave reduce
    float s = ((q0 == p) ? 0.f : h0a) + ((q0 + 1 == p) ? 0.f : h0b);
    #pragma unroll
    for (int off = 32; off > 0; off >>= 1)
        s += __shfl_down(s, off, 64);
    if (lane == 0) s_diag[c] = s * (1.0f / (NN - 1)) + bb0;

    __syncthreads();
    if (t < CCH) s_out[t][p] = s_diag[t];
    __syncthreads();

    // ---- phase 2: y[b,d,p,:] = relu(sum_c s_out[c]*Wc[d][c] + bc[d]) ----
    const int wv = t >> 6;             // 0..15 -> 8 d's each (wave-uniform)
    const int m0 = lane * 2;
    float rx[CCH], ry[CCH];
    #pragma unroll
    for (int cc = 0; cc < CCH; ++cc) {
        const float2 rv = *reinterpret_cast<const float2*>(&s_out[cc][m0]);
        rx[cc] = rv.x; ry[cc] = rv.y;
    }

    #pragma unroll 2
    for (int dd = 0; dd < 8; ++dd) {
        const int d = wv * 8 + dd;         // wave-uniform
        const float bcv = bc[d];           // scalar load
        float ax = bcv, ay = bcv;
        #pragma unroll
        for (int cc = 0; cc < CCH; ++cc) {
            const float wcf = Wc[d * CCH + cc];   // scalar load, SGPR operand
            ax = fmaf(wcf, rx[cc], ax);
            ay = fmaf(wcf, ry[cc], ay);
        }
        float2 ov;
        ov.x = fmaxf(ax, 0.f);
        ov.y = fmaxf(ay, 0.f);
        *reinterpret_cast<float2*>(
            &y[(((size_t)(b * DOUT + d)) * NN + p) * NN + m0]) = ov;
    }
}

__global__ __launch_bounds__(1024, 8) void fused_real(
    const float* __restrict__ x,
    const float* __restrict__ W1, const float* __restrict__ b1,
    const float* __restrict__ W2, const float* __restrict__ b2,
    const float* __restrict__ Wc, const float* __restrict__ bc,
    float* __restrict__ y)
{
    rey_body<1>(x, W1, b1, W2, b2, Wc, bc, y);
}

// shadow: identical structure, 3x k-loop, writes to ws — exists only to rise
// above the fillBuffer rows in the rocprof top-5 so we get counters.
__global__ __launch_bounds__(1024, 8) void fused_shadow(
    const float* __restrict__ x,
    const float* __restrict__ W1, const float* __restrict__ b1,
    const float* __restrict__ W2, const float* __restrict__ b2,
    const float* __restrict__ Wc, const float* __restrict__ bc,
    float* __restrict__ yws)
{
    rey_body<3>(x, W1, b1, W2, b2, Wc, bc, yws);
}

extern "C" void kernel_launch(void* const* d_in, const int* in_sizes, int n_in,
                              void* d_out, int out_size, void* d_ws, size_t ws_size,
                              hipStream_t stream) {
    const float* x  = (const float*)d_in[0];
    const float* W1 = (const float*)d_in[1];
    const float* b1 = (const float*)d_in[2];
    const float* W2 = (const float*)d_in[3];
    const float* b2 = (const float*)d_in[4];
    const float* Wc = (const float*)d_in[5];
    const float* bc = (const float*)d_in[6];
    float* y  = (float*)d_out;
    float* ws = (float*)d_ws;   // shadow output: 8.4M floats = 33.5 MB

    fused_real  <<<dim3(BB * NN), 1024, 0, stream>>>(x, W1, b1, W2, b2, Wc, bc, y);
    fused_shadow<<<dim3(BB * NN), 1024, 0, stream>>>(x, W1, b1, W2, b2, Wc, bc, ws);
}

// Round 13
// 36.576 us; speedup vs baseline: 6.6985x; 6.6985x over previous
//
#include <hip/hip_runtime.h>

#define NN 128
#define CCH 16
#define BB 4
#define HID 128
#define DOUT 128

typedef float v2f __attribute__((ext_vector_type(2)));

// ---------------------------------------------------------------------------
// Single fused kernel (R11 structure, unchanged except the block swizzle).
// Block = (b, row p), 1024 threads = 16 waves, 2 blocks/CU, 8192 waves total.
//
// XCD swizzle: the 8 XCDs get blockIdx round-robin (bid%8). Remapping
//   bid = (orig&7)*64 + orig>>3  gives each XCD a CONTIGUOUS 64-block range
// (one b, 64 consecutive p). Its working set of strided x lines (column
// lines shared by 16 adjacent p, diagonal shared by all p) is ~3-4 MB and
// fits the 4 MiB per-XCD L2 -> the strided xqp/xqq reads become L2 hits
// instead of the measured 236 MB HBM re-fetch (R12 shadow counters).
// ---------------------------------------------------------------------------
__global__ __launch_bounds__(1024, 8) void fused_rey(
    const float* __restrict__ x,
    const float* __restrict__ W1, const float* __restrict__ b1,
    const float* __restrict__ W2, const float* __restrict__ b2,
    const float* __restrict__ Wc, const float* __restrict__ bc,
    float* __restrict__ y)
{
    __shared__ float s_out[CCH][NN];   // 8 KB
    __shared__ float s_diag[CCH];

    const int t    = threadIdx.x;
    const int bid0 = blockIdx.x;
    const int bid  = ((bid0 & 7) << 6) | (bid0 >> 3);   // XCD-contiguous ranges
    const int p    = bid & 127;
    const int b    = bid >> 7;
    const int c    = t >> 6;           // 0..15, wave-uniform
    const int lane = t & 63;
    const int q0   = lane * 2;         // q pair {q0, q0+1}

    const size_t mbase = (size_t)(b * CCH + c) << 14;
    const float* xm = x + mbase;

    // per-thread x loads
    const v2f xpq = *reinterpret_cast<const v2f*>(&xm[p * NN + q0]);   // coalesced
    const v2f xqp = { xm[q0 * NN + p], xm[(q0 + 1) * NN + p] };        // strided (L2 after swizzle)
    const v2f xqq = { xm[q0 * (NN + 1)], xm[(q0 + 1) * (NN + 1)] };    // strided (L2 after swizzle)
    const float xpp = xm[p * (NN + 1)];                                // wave-uniform
    const v2f xpp2 = { xpp, xpp };

    const float bb0 = b2[0], bb1 = b2[1];
    const v2f z2 = { 0.f, 0.f };
    v2f h0 = z2, h1 = z2;

    // ---- phase 1: hidden loop ----
    #pragma unroll 4
    for (int k = 0; k < HID; ++k) {
        const float4 w  = reinterpret_cast<const float4*>(W1)[k];  // uniform -> s_load
        const float b1k = b1[k];
        const float w20 = W2[k];
        const float w21 = W2[HID + k];
        v2f hd = __builtin_elementwise_fma((v2f){ w.x, w.x }, xpp2, (v2f){ b1k, b1k });
        hd = __builtin_elementwise_fma((v2f){ w.y, w.y }, xpq, hd);
        hd = __builtin_elementwise_fma((v2f){ w.z, w.z }, xqp, hd);
        hd = __builtin_elementwise_fma((v2f){ w.w, w.w }, xqq, hd);
        hd = __builtin_elementwise_max(hd, z2);
        h0 = __builtin_elementwise_fma((v2f){ w20, w20 }, hd, h0);
        h1 = __builtin_elementwise_fma((v2f){ w21, w21 }, hd, h1);
    }

    // off-diagonal h1 (+b2[1]) -> LDS row c; (c, p) slot fixed after barrier
    const v2f o = h1 + (v2f){ bb1, bb1 };
    *reinterpret_cast<v2f*>(&s_out[c][q0]) = o;

    // diag partial: mask q==p, 64-lane wave reduce
    float s = ((q0 == p) ? 0.f : h0[0]) + ((q0 + 1 == p) ? 0.f : h0[1]);
    #pragma unroll
    for (int off = 32; off > 0; off >>= 1)
        s += __shfl_down(s, off, 64);
    if (lane == 0) s_diag[c] = s * (1.0f / (NN - 1)) + bb0;

    __syncthreads();
    if (t < CCH) s_out[t][p] = s_diag[t];
    __syncthreads();

    // ---- phase 2: y[b,d,p,:] = relu(sum_c s_out[c]*Wc[d][c] + bc[d]) ----
    const int wv = t >> 6;             // 0..15 -> 8 d's each
    const int m0 = lane * 2;
    v2f r[CCH];
    #pragma unroll
    for (int cc = 0; cc < CCH; ++cc)
        r[cc] = *reinterpret_cast<const v2f*>(&s_out[cc][m0]);

    #pragma unroll 2
    for (int dd = 0; dd < 8; ++dd) {
        const int d = wv * 8 + dd;         // wave-uniform
        const float bcv = bc[d];           // scalar load
        v2f acc = { bcv, bcv };
        #pragma unroll
        for (int cc = 0; cc < CCH; ++cc) {
            const float wcf = Wc[d * CCH + cc];   // scalar load
            acc = __builtin_elementwise_fma((v2f){ wcf, wcf }, r[cc], acc);
        }
        acc = __builtin_elementwise_max(acc, z2);
        *reinterpret_cast<v2f*>(
            &y[(((size_t)(b * DOUT + d)) * NN + p) * NN + m0]) = acc;
    }
}

extern "C" void kernel_launch(void* const* d_in, const int* in_sizes, int n_in,
                              void* d_out, int out_size, void* d_ws, size_t ws_size,
                              hipStream_t stream) {
    const float* x  = (const float*)d_in[0];
    const float* W1 = (const float*)d_in[1];
    const float* b1 = (const float*)d_in[2];
    const float* W2 = (const float*)d_in[3];
    const float* b2 = (const float*)d_in[4];
    const float* Wc = (const float*)d_in[5];
    const float* bc = (const float*)d_in[6];
    float* y = (float*)d_out;

    fused_rey<<<dim3(BB * NN), 1024, 0, stream>>>(x, W1, b1, W2, b2, Wc, bc, y);
}